// Round 3
// baseline (4137.664 us; speedup 1.0000x reference)
//
#include <hip/hip_runtime.h>
#include <hip/hip_bf16.h>
#include <math.h>

// Shapes: B=256, L=64, V=32000, D=1024, E=8, K=2, H=512, IMG=128
#define BATCH 256
#define CHUNK 32
#define NCHUNK (BATCH / CHUNK)
#define ECAP 256   // max tokens per (expert, modality): top-2 distinct => <= 256
#define NEXP 16    // 8 experts x 2 modalities

// ---------------- conv1: 3->32, 128x128, stride 1, SAME (pad 1/1) ----------------
__global__ __launch_bounds__(256) void conv1_tiled(const float* __restrict__ in,
                                                   const float* __restrict__ w,
                                                   const float* __restrict__ bias,
                                                   float* __restrict__ out) {
  const int t = threadIdx.x;
  const int bc = blockIdx.x;          // ((b*32 + co)*4 + quad)
  const int quad = bc & 3;
  const int co = (bc >> 2) & 31;
  const int b = bc >> 7;
  const int tile = quad * 256 + t;    // 0..1023
  const int tr = tile >> 4;           // 0..63
  const int tc = tile & 15;           // 0..15
  const int oh0 = tr * 2, ow0 = tc * 8;

  float wk[3][9];
#pragma unroll
  for (int ci = 0; ci < 3; ++ci)
#pragma unroll
    for (int k = 0; k < 9; ++k) wk[ci][k] = w[(co * 3 + ci) * 9 + k];

  const float bv = bias[co];
  float acc[2][8];
#pragma unroll
  for (int r = 0; r < 2; ++r)
#pragma unroll
    for (int c = 0; c < 8; ++c) acc[r][c] = bv;

  const float* __restrict__ ip = in + (size_t)b * 3 * 128 * 128;
#pragma unroll
  for (int ci = 0; ci < 3; ++ci) {
    const float* __restrict__ p = ip + ci * 128 * 128;
    float x[4][10];
#pragma unroll
    for (int r = 0; r < 4; ++r) {
      const int ih = oh0 - 1 + r;
      if (ih >= 0 && ih < 128) {
        const float* rowp = p + ih * 128 + ow0;
        x[r][0] = (ow0 > 0) ? rowp[-1] : 0.f;
        const float4 f0 = *(const float4*)(rowp);
        const float4 f1 = *(const float4*)(rowp + 4);
        x[r][1] = f0.x; x[r][2] = f0.y; x[r][3] = f0.z; x[r][4] = f0.w;
        x[r][5] = f1.x; x[r][6] = f1.y; x[r][7] = f1.z; x[r][8] = f1.w;
        x[r][9] = (ow0 + 8 < 128) ? rowp[8] : 0.f;
      } else {
#pragma unroll
        for (int q = 0; q < 10; ++q) x[r][q] = 0.f;
      }
    }
#pragma unroll
    for (int kh = 0; kh < 3; ++kh)
#pragma unroll
      for (int kw = 0; kw < 3; ++kw) {
        const float wv = wk[ci][kh * 3 + kw];
#pragma unroll
        for (int r = 0; r < 2; ++r)
#pragma unroll
          for (int c = 0; c < 8; ++c)
            acc[r][c] = fmaf(x[r + kh][c + kw], wv, acc[r][c]);
      }
  }
  float* __restrict__ op = out + (((size_t)b * 32 + co) * 128 + oh0) * 128 + ow0;
#pragma unroll
  for (int r = 0; r < 2; ++r)
#pragma unroll
    for (int c = 0; c < 8; ++c) op[r * 128 + c] = fmaxf(acc[r][c], 0.f);
}

// ------- stride-2 SAME convs (pad_lo=0, pad_hi=1), 4-co register blocking -------
// Each wave: one co-group of 4 (wave-uniform via readfirstlane -> weights s_load),
// each lane: TH x TW output tile. SLABS = spatial tiles / 64.
template<int CIN, int HIN, int WIN, int HOUT, int WOUT, int COUT, int TH, int TW, int SLABS>
__global__ __launch_bounds__(256) void conv_s2_r4(const float* __restrict__ in,
                                                  const float* __restrict__ w,
                                                  const float* __restrict__ bias,
                                                  float* __restrict__ out) {
  constexpr int TPR = WOUT / TW;
  constexpr int TT = (HOUT / TH) * TPR;
  static_assert(TT == 64 * SLABS, "tile count mismatch");
  constexpr int GPI = (SLABS == 4) ? (COUT / 4) : (COUT / 16);
  const int wave = threadIdx.x >> 6;
  const int lane = threadIdx.x & 63;
  const int b = blockIdx.x / GPI;
  const int r = blockIdx.x % GPI;
  int cg, slab;
  if (SLABS == 4) { cg = r; slab = wave; }
  else           { cg = r * 4 + wave; slab = 0; }
  const int co0 = __builtin_amdgcn_readfirstlane(cg * 4);
  const int tile = slab * 64 + lane;
  const int tr = tile / TPR, tc = tile % TPR;
  const int oh0 = tr * TH, ow0 = tc * TW;
  const int ih0 = oh0 * 2, iw0 = ow0 * 2;

  const float* __restrict__ ip = in + (size_t)b * CIN * HIN * WIN + ih0 * WIN + iw0;
  const float* __restrict__ wp = w + (size_t)co0 * CIN * 9;

  float bv[4];
#pragma unroll
  for (int j = 0; j < 4; ++j) bv[j] = bias[co0 + j];
  float acc[4][TH][TW];
#pragma unroll
  for (int j = 0; j < 4; ++j)
#pragma unroll
    for (int rr = 0; rr < TH; ++rr)
#pragma unroll
      for (int c = 0; c < TW; ++c) acc[j][rr][c] = bv[j];

  for (int ci = 0; ci < CIN; ++ci) {
    float wk[4][9];
#pragma unroll
    for (int j = 0; j < 4; ++j)
#pragma unroll
      for (int k = 0; k < 9; ++k) wk[j][k] = wp[((size_t)j * CIN + ci) * 9 + k];

    float x[2 * TH + 1][2 * TW + 1];
    const float* __restrict__ rp = ip + (size_t)ci * HIN * WIN;
#pragma unroll
    for (int rr = 0; rr < 2 * TH + 1; ++rr) {
      const int ih = ih0 + rr;
      if (ih < HIN) {
        const float* rowp = rp + rr * WIN;
#pragma unroll
        for (int q = 0; q < (2 * TW) / 4; ++q) {
          const float4 f = *(const float4*)(rowp + q * 4);
          x[rr][q * 4 + 0] = f.x; x[rr][q * 4 + 1] = f.y;
          x[rr][q * 4 + 2] = f.z; x[rr][q * 4 + 3] = f.w;
        }
        x[rr][2 * TW] = (iw0 + 2 * TW < WIN) ? rowp[2 * TW] : 0.f;
      } else {
#pragma unroll
        for (int q = 0; q < 2 * TW + 1; ++q) x[rr][q] = 0.f;
      }
    }
#pragma unroll
    for (int kh = 0; kh < 3; ++kh)
#pragma unroll
      for (int kw = 0; kw < 3; ++kw) {
#pragma unroll
        for (int j = 0; j < 4; ++j) {
          const float wv = wk[j][kh * 3 + kw];
#pragma unroll
          for (int rr = 0; rr < TH; ++rr)
#pragma unroll
            for (int c = 0; c < TW; ++c)
              acc[j][rr][c] = fmaf(x[2 * rr + kh][2 * c + kw], wv, acc[j][rr][c]);
        }
      }
  }
#pragma unroll
  for (int j = 0; j < 4; ++j) {
    float* __restrict__ op = out + (((size_t)b * COUT + co0 + j) * HOUT + oh0) * WOUT + ow0;
#pragma unroll
    for (int rr = 0; rr < TH; ++rr)
#pragma unroll
      for (int c = 0; c < TW; ++c) op[rr * WOUT + c] = fmaxf(acc[j][rr][c], 0.f);
  }
}

// ---------------- mean pool 16x16 -> 1 ----------------
__global__ __launch_bounds__(64) void pool_mean(const float* __restrict__ in,
                                                float* __restrict__ out) {
  const int bc = blockIdx.x;
  const float* p = in + (size_t)bc * 256;
  float s = p[threadIdx.x] + p[threadIdx.x + 64] + p[threadIdx.x + 128] + p[threadIdx.x + 192];
#pragma unroll
  for (int off = 32; off; off >>= 1) s += __shfl_down(s, off);
  if (threadIdx.x == 0) out[bc] = s * (1.f / 256.f);
}

// ---------------- pooled[B,256] @ W[256,1024] + b ----------------
__global__ __launch_bounds__(256) void enc_proj(const float* __restrict__ pooled,
                                                const float* __restrict__ W,
                                                const float* __restrict__ bias,
                                                float* __restrict__ out) {
  __shared__ float xs[256];
  const int b = blockIdx.x;
  const int t = threadIdx.x;
  xs[t] = pooled[b * 256 + t];
  __syncthreads();
#pragma unroll
  for (int dd = 0; dd < 4; ++dd) {
    const int d = t + dd * 256;
    float acc = bias[d];
    for (int i = 0; i < 256; ++i) acc = fmaf(xs[i], W[i * 1024 + d], acc);
    out[b * 1024 + d] = acc;
  }
}

// ---------------- text: masked mean of embeddings ----------------
__global__ __launch_bounds__(256) void txt_encode(const int* __restrict__ tokens,
                                                  const int* __restrict__ mask,
                                                  const float* __restrict__ embed,
                                                  float* __restrict__ out) {
  __shared__ int toks[64];
  __shared__ float ms[64];
  const int b = blockIdx.x;
  const int t = threadIdx.x;
  if (t < 64) {
    toks[t] = tokens[b * 64 + t];
    ms[t] = (float)mask[b * 64 + t];
  }
  __syncthreads();
  float denom = 0.f;
  for (int l = 0; l < 64; ++l) denom += ms[l];
  denom = fmaxf(denom, 1.f);
  const float inv = 1.f / denom;
#pragma unroll
  for (int dd = 0; dd < 4; ++dd) {
    const int d = t + dd * 256;
    float acc = 0.f;
    for (int l = 0; l < 64; ++l)
      acc = fmaf(embed[(size_t)toks[l] * 1024 + d], ms[l], acc);
    out[b * 1024 + d] = acc * inv;
  }
}

// ---------------- zero expert counters ----------------
__global__ __launch_bounds__(64) void zero_cnt(int* __restrict__ cnt) {
  if (threadIdx.x < NEXP) cnt[threadIdx.x] = 0;
}

// ------- gate: logits, softmax, top-2, weights + slot scatter -------
__global__ __launch_bounds__(256) void gate_topk(const float* __restrict__ x,
                                                 const float* __restrict__ gw,
                                                 const float* __restrict__ gb,
                                                 float* __restrict__ probs_out,
                                                 float* __restrict__ sel_w,
                                                 int* __restrict__ slot_of,
                                                 int* __restrict__ cnt,
                                                 int* __restrict__ slot_tok,
                                                 int emod_base) {
  const int b = blockIdx.x;
  __shared__ float part[256];
  __shared__ float logits[8];
  const int e = threadIdx.x & 7;
  const int ch = threadIdx.x >> 3;
  float acc = 0.f;
  for (int d = ch * 32; d < ch * 32 + 32; ++d)
    acc = fmaf(x[b * 1024 + d], gw[d * 8 + e], acc);
  part[threadIdx.x] = acc;
  __syncthreads();
  if (threadIdx.x < 8) {
    float s = gb[threadIdx.x];
    for (int c = 0; c < 32; ++c) s += part[c * 8 + threadIdx.x];
    logits[threadIdx.x] = s;
  }
  __syncthreads();
  if (threadIdx.x == 0) {
    float mx = logits[0];
    for (int i = 1; i < 8; ++i) mx = fmaxf(mx, logits[i]);
    float pe[8], sum = 0.f;
    for (int i = 0; i < 8; ++i) { pe[i] = expf(logits[i] - mx); sum += pe[i]; }
    const float inv = 1.f / sum;
    int i0 = 0;
    for (int i = 1; i < 8; ++i) if (pe[i] > pe[i0]) i0 = i;
    int i1 = (i0 == 0) ? 1 : 0;
    for (int i = 0; i < 8; ++i) { if (i == i0) continue; if (pe[i] > pe[i1]) i1 = i; }
    for (int i = 0; i < 8; ++i) probs_out[b * 8 + i] = pe[i] * inv;
    const float v0 = pe[i0] * inv, v1 = pe[i1] * inv;
    const float wsum = v0 + v1 + 1e-9f;
    const int sel[2] = {i0, i1};
    const float sw[2] = {v0 / wsum, v1 / wsum};
#pragma unroll
    for (int k = 0; k < 2; ++k) {
      const int ve = emod_base + sel[k];
      const int slot = atomicAdd(&cnt[ve], 1);
      slot_tok[ve * ECAP + slot] = b;
      slot_of[b * 2 + k] = ve * ECAP + slot;
      sel_w[b * 2 + k] = sw[k];
    }
  }
}

// ------- MoE FFN part 1: h = relu(x @ W1 + b1), expert-grouped, 32x128 tiles -------
__global__ __launch_bounds__(256) void moe_ffn1(const float* __restrict__ h_img,
                                                const float* __restrict__ h_txt,
                                                const int* __restrict__ cnt,
                                                const int* __restrict__ slot_tok,
                                                const float* __restrict__ W1,
                                                const float* __restrict__ B1,
                                                float* __restrict__ hbuf) {
  const int ve = blockIdx.x >> 5;          // 0..15
  const int rem = blockIdx.x & 31;
  const int tchunk = rem >> 2;             // 0..7
  const int nchunk = rem & 3;              // 0..3
  const int tbase = tchunk * 32;
  const int scnt = cnt[ve];
  if (tbase >= scnt) return;
  const int n0 = nchunk * 128;
  const int e = ve & 7;
  const float* __restrict__ xsrc = (ve < 8) ? h_img : h_txt;
  const float* __restrict__ w1 = W1 + (size_t)e * 1024 * 512;

  __shared__ float xs[32][36];
  __shared__ float ws[32][128];

  const int tid = threadIdx.x;
  const int tokr = tid >> 3, kq = tid & 7;
  const int sidx = tbase + tokr;
  const int tok = (sidx < scnt) ? slot_tok[ve * ECAP + sidx] : 0;
  const int tn = tid & 31, tt = tid >> 5;
  const int n4 = tn * 4, t4 = tt * 4;

  float acc[4][4] = {};
  for (int k0 = 0; k0 < 1024; k0 += 32) {
    const float4 xv = *(const float4*)(xsrc + (size_t)tok * 1024 + k0 + kq * 4);
    float4 wv[4];
#pragma unroll
    for (int i = 0; i < 4; ++i) {
      const int idx = tid + i * 256;
      const int kk = idx >> 5, nq = idx & 31;
      wv[i] = *(const float4*)(w1 + (size_t)(k0 + kk) * 512 + n0 + nq * 4);
    }
    __syncthreads();
    xs[kq * 4 + 0][tokr] = xv.x; xs[kq * 4 + 1][tokr] = xv.y;
    xs[kq * 4 + 2][tokr] = xv.z; xs[kq * 4 + 3][tokr] = xv.w;
#pragma unroll
    for (int i = 0; i < 4; ++i) {
      const int idx = tid + i * 256;
      const int kk = idx >> 5, nq = idx & 31;
      *(float4*)&ws[kk][nq * 4] = wv[i];
    }
    __syncthreads();
#pragma unroll
    for (int k = 0; k < 32; ++k) {
      const float4 xr = *(const float4*)&xs[k][t4];
      const float4 wr = *(const float4*)&ws[k][n4];
      const float xa[4] = {xr.x, xr.y, xr.z, xr.w};
      const float wa[4] = {wr.x, wr.y, wr.z, wr.w};
#pragma unroll
      for (int ti = 0; ti < 4; ++ti)
#pragma unroll
        for (int ni = 0; ni < 4; ++ni)
          acc[ti][ni] = fmaf(xa[ti], wa[ni], acc[ti][ni]);
    }
  }
#pragma unroll
  for (int ti = 0; ti < 4; ++ti) {
    float* hp = hbuf + ((size_t)ve * ECAP + tbase + t4 + ti) * 512 + n0 + n4;
#pragma unroll
    for (int ni = 0; ni < 4; ++ni)
      hp[ni] = fmaxf(acc[ti][ni] + B1[e * 512 + n0 + n4 + ni], 0.f);
  }
}

// ------- MoE FFN part 2: y = h @ W2 + b2, expert-grouped, 32x128 tiles -------
__global__ __launch_bounds__(256) void moe_ffn2(const float* __restrict__ hbuf,
                                                const int* __restrict__ cnt,
                                                const float* __restrict__ W2,
                                                const float* __restrict__ B2,
                                                float* __restrict__ ybuf) {
  const int ve = blockIdx.x >> 6;          // 0..15
  const int rem = blockIdx.x & 63;
  const int tchunk = rem >> 3;             // 0..7
  const int nchunk = rem & 7;              // 0..7
  const int tbase = tchunk * 32;
  const int scnt = cnt[ve];
  if (tbase >= scnt) return;
  const int n0 = nchunk * 128;
  const int e = ve & 7;
  const float* __restrict__ w2 = W2 + (size_t)e * 512 * 1024;

  __shared__ float hs[32][36];
  __shared__ float ws[32][128];

  const int tid = threadIdx.x;
  const int tokr = tid >> 3, kq = tid & 7;
  const int tn = tid & 31, tt = tid >> 5;
  const int n4 = tn * 4, t4 = tt * 4;

  float acc[4][4] = {};
  for (int k0 = 0; k0 < 512; k0 += 32) {
    const float4 hv = *(const float4*)(hbuf + ((size_t)ve * ECAP + tbase + tokr) * 512 + k0 + kq * 4);
    float4 wv[4];
#pragma unroll
    for (int i = 0; i < 4; ++i) {
      const int idx = tid + i * 256;
      const int kk = idx >> 5, nq = idx & 31;
      wv[i] = *(const float4*)(w2 + (size_t)(k0 + kk) * 1024 + n0 + nq * 4);
    }
    __syncthreads();
    hs[kq * 4 + 0][tokr] = hv.x; hs[kq * 4 + 1][tokr] = hv.y;
    hs[kq * 4 + 2][tokr] = hv.z; hs[kq * 4 + 3][tokr] = hv.w;
#pragma unroll
    for (int i = 0; i < 4; ++i) {
      const int idx = tid + i * 256;
      const int kk = idx >> 5, nq = idx & 31;
      *(float4*)&ws[kk][nq * 4] = wv[i];
    }
    __syncthreads();
#pragma unroll
    for (int k = 0; k < 32; ++k) {
      const float4 xr = *(const float4*)&hs[k][t4];
      const float4 wr = *(const float4*)&ws[k][n4];
      const float xa[4] = {xr.x, xr.y, xr.z, xr.w};
      const float wa[4] = {wr.x, wr.y, wr.z, wr.w};
#pragma unroll
      for (int ti = 0; ti < 4; ++ti)
#pragma unroll
        for (int ni = 0; ni < 4; ++ni)
          acc[ti][ni] = fmaf(xa[ti], wa[ni], acc[ti][ni]);
    }
  }
#pragma unroll
  for (int ti = 0; ti < 4; ++ti) {
    float* yp = ybuf + ((size_t)ve * ECAP + tbase + t4 + ti) * 1024 + n0 + n4;
#pragma unroll
    for (int ni = 0; ni < 4; ++ni)
      yp[ni] = acc[ti][ni] + B2[e * 1024 + n0 + n4 + ni];
  }
}

// ------- combine: z[b] = w0*y[slot0] + w1*y[slot1] -------
__global__ __launch_bounds__(256) void moe_combine(const float* __restrict__ ybuf,
                                                   const int* __restrict__ slot_of,
                                                   const float* __restrict__ sel_w,
                                                   float* __restrict__ z_img,
                                                   float* __restrict__ z_txt) {
  const int bb = blockIdx.x;           // 0..511 (mod*256 + b)
  const int mod = bb >> 8;
  const int b = bb & 255;
  const int s0 = slot_of[bb * 2], s1 = slot_of[bb * 2 + 1];
  const float w0 = sel_w[bb * 2], w1 = sel_w[bb * 2 + 1];
  float* __restrict__ zp = (mod ? z_txt : z_img) + (size_t)b * 1024;
  const float* __restrict__ y0 = ybuf + (size_t)s0 * 1024;
  const float* __restrict__ y1 = ybuf + (size_t)s1 * 1024;
  const int t = threadIdx.x;
#pragma unroll
  for (int dd = 0; dd < 4; ++dd) {
    const int d = t + dd * 256;
    zp[d] = w0 * y0[d] + w1 * y1[d];
  }
}

// ---------------- z @ W[1024,1024], then L2-normalize ----------------
__global__ __launch_bounds__(256) void proj_norm(const float* __restrict__ z,
                                                 const float* __restrict__ W,
                                                 float* __restrict__ e_out) {
  const int b = blockIdx.x;
  const int t = threadIdx.x;
  __shared__ float xs[1024];
  __shared__ float red[256];
#pragma unroll
  for (int i = 0; i < 4; ++i) xs[t + i * 256] = z[b * 1024 + t + i * 256];
  __syncthreads();
  float p[4];
  float ss = 0.f;
#pragma unroll
  for (int dd = 0; dd < 4; ++dd) {
    const int d = t + dd * 256;
    float acc = 0.f;
    for (int i = 0; i < 1024; ++i) acc = fmaf(xs[i], W[i * 1024 + d], acc);
    p[dd] = acc;
    ss += acc * acc;
  }
  red[t] = ss;
  __syncthreads();
  for (int off = 128; off; off >>= 1) {
    if (t < off) red[t] += red[t + off];
    __syncthreads();
  }
  const float inv = 1.f / fmaxf(sqrtf(red[0]), 1e-12f);
#pragma unroll
  for (int dd = 0; dd < 4; ++dd) e_out[b * 1024 + t + dd * 256] = p[dd] * inv;
}

// ---------------- logits: scale * e_img @ e_txt^T (+ transpose) ----------------
__global__ __launch_bounds__(256) void clip_logits(const float* __restrict__ ei,
                                                   const float* __restrict__ et,
                                                   const float* __restrict__ logit_scale,
                                                   float* __restrict__ out_pi,
                                                   float* __restrict__ out_pt) {
  const int i = blockIdx.x;
  const int j = threadIdx.x;
  __shared__ float row[1024];
#pragma unroll
  for (int c = 0; c < 4; ++c) row[j + c * 256] = ei[i * 1024 + j + c * 256];
  __syncthreads();
  float acc = 0.f;
  const float* __restrict__ tp = et + (size_t)j * 1024;
  for (int d = 0; d < 1024; ++d) acc = fmaf(row[d], tp[d], acc);
  const float s = fminf(expf(logit_scale[0]), 100.f);
  const float v = s * acc;
  out_pi[i * 256 + j] = v;
  out_pt[j * 256 + i] = v;
}

// ---------------- aux loss (deterministic fixed-order reduce) ----------------
__global__ __launch_bounds__(256) void aux_kernel(const float* __restrict__ probs_i,
                                                  const float* __restrict__ probs_t,
                                                  float* __restrict__ out_aux) {
  __shared__ float red[256];
  const int t = threadIdx.x;
  float aux[2];
  for (int m = 0; m < 2; ++m) {
    const float* __restrict__ p = m ? probs_t : probs_i;
    float a = 0.f;
    for (int e = 0; e < 8; ++e) {
      red[t] = p[t * 8 + e];
      __syncthreads();
      for (int off = 128; off; off >>= 1) {
        if (t < off) red[t] += red[t + off];
        __syncthreads();
      }
      const float mp = red[0] * (1.f / 256.f);
      a += 0.125f * (logf(0.125f) - logf(mp));
      __syncthreads();
    }
    aux[m] = a * 0.125f;
  }
  if (t == 0) out_aux[0] = 0.5f * (aux[0] + aux[1]);
}

extern "C" void kernel_launch(void* const* d_in, const int* in_sizes, int n_in,
                              void* d_out, int out_size, void* d_ws, size_t ws_size,
                              hipStream_t stream) {
  const float* img        = (const float*)d_in[0];
  const int*   tokens     = (const int*)d_in[1];
  const int*   mask       = (const int*)d_in[2];
  const float* cw1        = (const float*)d_in[3];
  const float* cb1        = (const float*)d_in[4];
  const float* cw2        = (const float*)d_in[5];
  const float* cb2        = (const float*)d_in[6];
  const float* cw3        = (const float*)d_in[7];
  const float* cb3        = (const float*)d_in[8];
  const float* cw4        = (const float*)d_in[9];
  const float* cb4        = (const float*)d_in[10];
  const float* enc_proj_w = (const float*)d_in[11];
  const float* enc_proj_b = (const float*)d_in[12];
  const float* embed      = (const float*)d_in[13];
  const float* gate_w     = (const float*)d_in[14];
  const float* gate_b     = (const float*)d_in[15];
  const float* exp_w1     = (const float*)d_in[16];
  const float* exp_b1     = (const float*)d_in[17];
  const float* exp_w2     = (const float*)d_in[18];
  const float* exp_b2     = (const float*)d_in[19];
  const float* img_proj_w = (const float*)d_in[20];
  const float* txt_proj_w = (const float*)d_in[21];
  const float* logit_sc   = (const float*)d_in[22];
  float* out = (float*)d_out;

  // workspace layout (floats)
  float* bufA   = (float*)d_ws;           // 16,777,216 floats (64 MB)
  float* bufB   = bufA + 16777216;        //  8,388,608 floats (32 MB)
  float* pooled = bufB + 8388608;         // 65,536
  float* h_img  = pooled + 65536;         // 262,144
  float* h_txt  = h_img + 262144;
  float* z_img  = h_txt + 262144;
  float* z_txt  = z_img + 262144;
  float* e_img  = z_txt + 262144;
  float* e_txt  = e_img + 262144;
  float* probs_img = e_txt + 262144;      // 2048
  float* probs_txt = probs_img + 2048;    // 2048
  float* sel_w  = probs_txt + 2048;       // 1024 (2 modalities x 256 x 2)
  int* slot_of  = (int*)(sel_w + 1024);   // 1024
  int* slot_tok = slot_of + 1024;         // NEXP*ECAP = 4096
  int* cnt      = slot_tok + 4096;        // 16
  // MoE intermediate buffers overlay bufA (convs finished before MoE runs)
  float* hbuf = bufA;                     // 4096 x 512  (8 MB)
  float* ybuf = bufA + (size_t)NEXP * ECAP * 512;  // 4096 x 1024 (16 MB)

  zero_cnt<<<1, 64, 0, stream>>>(cnt);

  // ---- image encoder, chunked ----
  for (int c = 0; c < NCHUNK; ++c) {
    const float* imgc = img + (size_t)c * CHUNK * 3 * 128 * 128;
    conv1_tiled<<<CHUNK * 32 * 4, 256, 0, stream>>>(imgc, cw1, cb1, bufA);
    conv_s2_r4<32, 128, 128, 64, 64, 64, 2, 8, 4>
        <<<CHUNK * 16, 256, 0, stream>>>(bufA, cw2, cb2, bufB);
    conv_s2_r4<64, 64, 64, 32, 32, 128, 2, 8, 1>
        <<<CHUNK * 8, 256, 0, stream>>>(bufB, cw3, cb3, bufA);
    conv_s2_r4<128, 32, 32, 16, 16, 256, 2, 2, 1>
        <<<CHUNK * 16, 256, 0, stream>>>(bufA, cw4, cb4, bufB);
    pool_mean<<<CHUNK * 256, 64, 0, stream>>>(bufB, pooled + (size_t)c * CHUNK * 256);
  }
  enc_proj<<<BATCH, 256, 0, stream>>>(pooled, enc_proj_w, enc_proj_b, h_img);

  // ---- text encoder ----
  txt_encode<<<BATCH, 256, 0, stream>>>(tokens, mask, embed, h_txt);

  // ---- MoE: gate + scatter, grouped FFN, combine ----
  gate_topk<<<BATCH, 256, 0, stream>>>(h_img, gate_w, gate_b, probs_img,
                                       sel_w, slot_of, cnt, slot_tok, 0);
  gate_topk<<<BATCH, 256, 0, stream>>>(h_txt, gate_w, gate_b, probs_txt,
                                       sel_w + 512, slot_of + 512, cnt, slot_tok, 8);
  moe_ffn1<<<NEXP * 32, 256, 0, stream>>>(h_img, h_txt, cnt, slot_tok,
                                          exp_w1, exp_b1, hbuf);
  moe_ffn2<<<NEXP * 64, 256, 0, stream>>>(hbuf, cnt, exp_w2, exp_b2, ybuf);
  moe_combine<<<512, 256, 0, stream>>>(ybuf, slot_of, sel_w, z_img, z_txt);

  // ---- contrastive head ----
  proj_norm<<<BATCH, 256, 0, stream>>>(z_img, img_proj_w, e_img);
  proj_norm<<<BATCH, 256, 0, stream>>>(z_txt, txt_proj_w, e_txt);
  clip_logits<<<BATCH, 256, 0, stream>>>(e_img, e_txt, logit_sc, out, out + 65536);
  aux_kernel<<<1, 256, 0, stream>>>(probs_img, probs_txt, out + 131072);
}

// Round 13
// 3874.693 us; speedup vs baseline: 1.0679x; 1.0679x over previous
//
#include <hip/hip_runtime.h>
#include <hip/hip_bf16.h>
#include <math.h>

// Shapes: B=256, L=64, V=32000, D=1024, E=8, K=2, H=512, IMG=128
#define BATCH 256
#define ECAP 256   // max tokens per (expert, modality)
#define NEXP 16    // 8 experts x 2 modalities

// ---------------- conv1: 3->32, 128x128, stride 1, SAME (pad 1/1) ----------------
__global__ __launch_bounds__(256) void conv1_tiled(const float* __restrict__ in,
                                                   const float* __restrict__ w,
                                                   const float* __restrict__ bias,
                                                   float* __restrict__ out) {
  const int t = threadIdx.x;
  const int bc = blockIdx.x;          // ((b*32 + co)*4 + quad)
  const int quad = bc & 3;
  const int co = (bc >> 2) & 31;
  const int b = bc >> 7;
  const int tile = quad * 256 + t;    // 0..1023
  const int tr = tile >> 4;           // 0..63
  const int tc = tile & 15;           // 0..15
  const int oh0 = tr * 2, ow0 = tc * 8;

  float wk[3][9];
#pragma unroll
  for (int ci = 0; ci < 3; ++ci)
#pragma unroll
    for (int k = 0; k < 9; ++k) wk[ci][k] = w[(co * 3 + ci) * 9 + k];

  const float bv = bias[co];
  float acc[2][8];
#pragma unroll
  for (int r = 0; r < 2; ++r)
#pragma unroll
    for (int c = 0; c < 8; ++c) acc[r][c] = bv;

  const float* __restrict__ ip = in + (size_t)b * 3 * 128 * 128;
#pragma unroll
  for (int ci = 0; ci < 3; ++ci) {
    const float* __restrict__ p = ip + ci * 128 * 128;
    float x[4][10];
#pragma unroll
    for (int r = 0; r < 4; ++r) {
      const int ih = oh0 - 1 + r;
      if (ih >= 0 && ih < 128) {
        const float* rowp = p + ih * 128 + ow0;
        x[r][0] = (ow0 > 0) ? rowp[-1] : 0.f;
        const float4 f0 = *(const float4*)(rowp);
        const float4 f1 = *(const float4*)(rowp + 4);
        x[r][1] = f0.x; x[r][2] = f0.y; x[r][3] = f0.z; x[r][4] = f0.w;
        x[r][5] = f1.x; x[r][6] = f1.y; x[r][7] = f1.z; x[r][8] = f1.w;
        x[r][9] = (ow0 + 8 < 128) ? rowp[8] : 0.f;
      } else {
#pragma unroll
        for (int q = 0; q < 10; ++q) x[r][q] = 0.f;
      }
    }
#pragma unroll
    for (int kh = 0; kh < 3; ++kh)
#pragma unroll
      for (int kw = 0; kw < 3; ++kw) {
        const float wv = wk[ci][kh * 3 + kw];
#pragma unroll
        for (int r = 0; r < 2; ++r)
#pragma unroll
          for (int c = 0; c < 8; ++c)
            acc[r][c] = fmaf(x[r + kh][c + kw], wv, acc[r][c]);
      }
  }
  float* __restrict__ op = out + (((size_t)b * 32 + co) * 128 + oh0) * 128 + ow0;
#pragma unroll
  for (int r = 0; r < 2; ++r)
#pragma unroll
    for (int c = 0; c < 8; ++c) op[r * 128 + c] = fmaxf(acc[r][c], 0.f);
}

// ------- stride-2 SAME convs (pad_lo=0, pad_hi=1), 4-co register blocking -------
template<int CIN, int HIN, int WIN, int HOUT, int WOUT, int COUT, int TH, int TW, int SLABS>
__global__ __launch_bounds__(256) void conv_s2_r4(const float* __restrict__ in,
                                                  const float* __restrict__ w,
                                                  const float* __restrict__ bias,
                                                  float* __restrict__ out) {
  constexpr int TPR = WOUT / TW;
  constexpr int TT = (HOUT / TH) * TPR;
  static_assert(TT == 64 * SLABS, "tile count mismatch");
  constexpr int GPI = (SLABS == 4) ? (COUT / 4) : (COUT / 16);
  const int wave = threadIdx.x >> 6;
  const int lane = threadIdx.x & 63;
  const int b = blockIdx.x / GPI;
  const int r = blockIdx.x % GPI;
  int cg, slab;
  if (SLABS == 4) { cg = r; slab = wave; }
  else           { cg = r * 4 + wave; slab = 0; }
  const int co0 = __builtin_amdgcn_readfirstlane(cg * 4);
  const int tile = slab * 64 + lane;
  const int tr = tile / TPR, tc = tile % TPR;
  const int oh0 = tr * TH, ow0 = tc * TW;
  const int ih0 = oh0 * 2, iw0 = ow0 * 2;

  const float* __restrict__ ip = in + (size_t)b * CIN * HIN * WIN + ih0 * WIN + iw0;
  const float* __restrict__ wp = w + (size_t)co0 * CIN * 9;

  float bv[4];
#pragma unroll
  for (int j = 0; j < 4; ++j) bv[j] = bias[co0 + j];
  float acc[4][TH][TW];
#pragma unroll
  for (int j = 0; j < 4; ++j)
#pragma unroll
    for (int rr = 0; rr < TH; ++rr)
#pragma unroll
      for (int c = 0; c < TW; ++c) acc[j][rr][c] = bv[j];

  for (int ci = 0; ci < CIN; ++ci) {
    float wk[4][9];
#pragma unroll
    for (int j = 0; j < 4; ++j)
#pragma unroll
      for (int k = 0; k < 9; ++k) wk[j][k] = wp[((size_t)j * CIN + ci) * 9 + k];

    float x[2 * TH + 1][2 * TW + 1];
    const float* __restrict__ rp = ip + (size_t)ci * HIN * WIN;
#pragma unroll
    for (int rr = 0; rr < 2 * TH + 1; ++rr) {
      const int ih = ih0 + rr;
      if (ih < HIN) {
        const float* rowp = rp + rr * WIN;
#pragma unroll
        for (int q = 0; q < (2 * TW) / 4; ++q) {
          const float4 f = *(const float4*)(rowp + q * 4);
          x[rr][q * 4 + 0] = f.x; x[rr][q * 4 + 1] = f.y;
          x[rr][q * 4 + 2] = f.z; x[rr][q * 4 + 3] = f.w;
        }
        x[rr][2 * TW] = (iw0 + 2 * TW < WIN) ? rowp[2 * TW] : 0.f;
      } else {
#pragma unroll
        for (int q = 0; q < 2 * TW + 1; ++q) x[rr][q] = 0.f;
      }
    }
#pragma unroll
    for (int kh = 0; kh < 3; ++kh)
#pragma unroll
      for (int kw = 0; kw < 3; ++kw) {
#pragma unroll
        for (int j = 0; j < 4; ++j) {
          const float wv = wk[j][kh * 3 + kw];
#pragma unroll
          for (int rr = 0; rr < TH; ++rr)
#pragma unroll
            for (int c = 0; c < TW; ++c)
              acc[j][rr][c] = fmaf(x[2 * rr + kh][2 * c + kw], wv, acc[j][rr][c]);
        }
      }
  }
#pragma unroll
  for (int j = 0; j < 4; ++j) {
    float* __restrict__ op = out + (((size_t)b * COUT + co0 + j) * HOUT + oh0) * WOUT + ow0;
#pragma unroll
    for (int rr = 0; rr < TH; ++rr)
#pragma unroll
      for (int c = 0; c < TW; ++c) op[rr * WOUT + c] = fmaxf(acc[j][rr][c], 0.f);
  }
}

// ------- conv4 fused with 16x16 mean-pool: 128->256, 32->16, output pooled[b][co] -------
__global__ __launch_bounds__(256) void conv4_pool(const float* __restrict__ in,
                                                  const float* __restrict__ w,
                                                  const float* __restrict__ bias,
                                                  float* __restrict__ pooled) {
  constexpr int CIN = 128, HIN = 32, WIN = 32;
  const int wave = threadIdx.x >> 6;
  const int lane = threadIdx.x & 63;
  const int b = blockIdx.x >> 4;          // 16 groups per image
  const int r = blockIdx.x & 15;
  const int cg = r * 4 + wave;            // 64 co-groups of 4
  const int co0 = __builtin_amdgcn_readfirstlane(cg * 4);
  const int tr = lane >> 3, tc = lane & 7;  // 8x8 tiles of 2x2
  const int oh0 = tr * 2, ow0 = tc * 2;
  const int ih0 = oh0 * 2, iw0 = ow0 * 2;

  const float* __restrict__ ip = in + (size_t)b * CIN * HIN * WIN + ih0 * WIN + iw0;
  const float* __restrict__ wp = w + (size_t)co0 * CIN * 9;

  float bv[4];
#pragma unroll
  for (int j = 0; j < 4; ++j) bv[j] = bias[co0 + j];
  float acc[4][2][2];
#pragma unroll
  for (int j = 0; j < 4; ++j)
#pragma unroll
    for (int rr = 0; rr < 2; ++rr)
#pragma unroll
      for (int c = 0; c < 2; ++c) acc[j][rr][c] = bv[j];

  for (int ci = 0; ci < CIN; ++ci) {
    float wk[4][9];
#pragma unroll
    for (int j = 0; j < 4; ++j)
#pragma unroll
      for (int k = 0; k < 9; ++k) wk[j][k] = wp[((size_t)j * CIN + ci) * 9 + k];

    float x[5][5];
    const float* __restrict__ rp = ip + (size_t)ci * HIN * WIN;
#pragma unroll
    for (int rr = 0; rr < 5; ++rr) {
      const int ih = ih0 + rr;
      if (ih < HIN) {
        const float* rowp = rp + rr * WIN;
        const float4 f = *(const float4*)(rowp);
        x[rr][0] = f.x; x[rr][1] = f.y; x[rr][2] = f.z; x[rr][3] = f.w;
        x[rr][4] = (iw0 + 4 < WIN) ? rowp[4] : 0.f;
      } else {
#pragma unroll
        for (int q = 0; q < 5; ++q) x[rr][q] = 0.f;
      }
    }
#pragma unroll
    for (int kh = 0; kh < 3; ++kh)
#pragma unroll
      for (int kw = 0; kw < 3; ++kw) {
#pragma unroll
        for (int j = 0; j < 4; ++j) {
          const float wv = wk[j][kh * 3 + kw];
#pragma unroll
          for (int rr = 0; rr < 2; ++rr)
#pragma unroll
            for (int c = 0; c < 2; ++c)
              acc[j][rr][c] = fmaf(x[2 * rr + kh][2 * c + kw], wv, acc[j][rr][c]);
        }
      }
  }
  float s[4];
#pragma unroll
  for (int j = 0; j < 4; ++j)
    s[j] = fmaxf(acc[j][0][0], 0.f) + fmaxf(acc[j][0][1], 0.f) +
           fmaxf(acc[j][1][0], 0.f) + fmaxf(acc[j][1][1], 0.f);
#pragma unroll
  for (int off = 32; off; off >>= 1) {
#pragma unroll
    for (int j = 0; j < 4; ++j) s[j] += __shfl_down(s[j], off);
  }
  if (lane == 0) {
#pragma unroll
    for (int j = 0; j < 4; ++j)
      pooled[b * 256 + co0 + j] = s[j] * (1.f / 256.f);
  }
}

// ---------------- pooled[B,256] @ W[256,1024] + b ----------------
__global__ __launch_bounds__(256) void enc_proj(const float* __restrict__ pooled,
                                                const float* __restrict__ W,
                                                const float* __restrict__ bias,
                                                float* __restrict__ out) {
  __shared__ float xs[256];
  const int b = blockIdx.x;
  const int t = threadIdx.x;
  xs[t] = pooled[b * 256 + t];
  __syncthreads();
#pragma unroll
  for (int dd = 0; dd < 4; ++dd) {
    const int d = t + dd * 256;
    float acc = bias[d];
    for (int i = 0; i < 256; ++i) acc = fmaf(xs[i], W[i * 1024 + d], acc);
    out[b * 1024 + d] = acc;
  }
}

// ---------------- text: masked mean of embeddings ----------------
__global__ __launch_bounds__(256) void txt_encode(const int* __restrict__ tokens,
                                                  const int* __restrict__ mask,
                                                  const float* __restrict__ embed,
                                                  float* __restrict__ out) {
  __shared__ int toks[64];
  __shared__ float ms[64];
  const int b = blockIdx.x;
  const int t = threadIdx.x;
  if (t < 64) {
    toks[t] = tokens[b * 64 + t];
    ms[t] = (float)mask[b * 64 + t];
  }
  __syncthreads();
  float denom = 0.f;
  for (int l = 0; l < 64; ++l) denom += ms[l];
  denom = fmaxf(denom, 1.f);
  const float inv = 1.f / denom;
#pragma unroll
  for (int dd = 0; dd < 4; ++dd) {
    const int d = t + dd * 256;
    float acc = 0.f;
    for (int l = 0; l < 64; ++l)
      acc = fmaf(embed[(size_t)toks[l] * 1024 + d], ms[l], acc);
    out[b * 1024 + d] = acc * inv;
  }
}

// ---------------- zero expert counters ----------------
__global__ __launch_bounds__(64) void zero_cnt(int* __restrict__ cnt) {
  if (threadIdx.x < NEXP) cnt[threadIdx.x] = 0;
}

// ------- gate: logits, softmax, top-2, weights + slot scatter -------
__global__ __launch_bounds__(256) void gate_topk(const float* __restrict__ x,
                                                 const float* __restrict__ gw,
                                                 const float* __restrict__ gb,
                                                 float* __restrict__ probs_out,
                                                 float* __restrict__ sel_w,
                                                 int* __restrict__ slot_of,
                                                 int* __restrict__ cnt,
                                                 int* __restrict__ slot_tok,
                                                 int emod_base) {
  const int b = blockIdx.x;
  __shared__ float part[256];
  __shared__ float logits[8];
  const int e = threadIdx.x & 7;
  const int ch = threadIdx.x >> 3;
  float acc = 0.f;
  for (int d = ch * 32; d < ch * 32 + 32; ++d)
    acc = fmaf(x[b * 1024 + d], gw[d * 8 + e], acc);
  part[threadIdx.x] = acc;
  __syncthreads();
  if (threadIdx.x < 8) {
    float s = gb[threadIdx.x];
    for (int c = 0; c < 32; ++c) s += part[c * 8 + threadIdx.x];
    logits[threadIdx.x] = s;
  }
  __syncthreads();
  if (threadIdx.x == 0) {
    float mx = logits[0];
    for (int i = 1; i < 8; ++i) mx = fmaxf(mx, logits[i]);
    float pe[8], sum = 0.f;
    for (int i = 0; i < 8; ++i) { pe[i] = expf(logits[i] - mx); sum += pe[i]; }
    const float inv = 1.f / sum;
    int i0 = 0;
    for (int i = 1; i < 8; ++i) if (pe[i] > pe[i0]) i0 = i;
    int i1 = (i0 == 0) ? 1 : 0;
    for (int i = 0; i < 8; ++i) { if (i == i0) continue; if (pe[i] > pe[i1]) i1 = i; }
    for (int i = 0; i < 8; ++i) probs_out[b * 8 + i] = pe[i] * inv;
    const float v0 = pe[i0] * inv, v1 = pe[i1] * inv;
    const float wsum = v0 + v1 + 1e-9f;
    const int sel[2] = {i0, i1};
    const float sw[2] = {v0 / wsum, v1 / wsum};
#pragma unroll
    for (int k = 0; k < 2; ++k) {
      const int ve = emod_base + sel[k];
      const int slot = atomicAdd(&cnt[ve], 1);
      slot_tok[ve * ECAP + slot] = b;
      slot_of[b * 2 + k] = ve * ECAP + slot;
      sel_w[b * 2 + k] = sw[k];
    }
  }
}

// ------- MoE FFN part 1: h = relu(x @ W1 + b1), expert-grouped, 32x128 tiles -------
__global__ __launch_bounds__(256) void moe_ffn1(const float* __restrict__ h_img,
                                                const float* __restrict__ h_txt,
                                                const int* __restrict__ cnt,
                                                const int* __restrict__ slot_tok,
                                                const float* __restrict__ W1,
                                                const float* __restrict__ B1,
                                                float* __restrict__ hbuf) {
  const int ve = blockIdx.x >> 5;
  const int rem = blockIdx.x & 31;
  const int tchunk = rem >> 2;
  const int nchunk = rem & 3;
  const int tbase = tchunk * 32;
  const int scnt = cnt[ve];
  if (tbase >= scnt) return;
  const int n0 = nchunk * 128;
  const int e = ve & 7;
  const float* __restrict__ xsrc = (ve < 8) ? h_img : h_txt;
  const float* __restrict__ w1 = W1 + (size_t)e * 1024 * 512;

  __shared__ float xs[32][36];
  __shared__ float ws[32][128];

  const int tid = threadIdx.x;
  const int tokr = tid >> 3, kq = tid & 7;
  const int sidx = tbase + tokr;
  const int tok = (sidx < scnt) ? slot_tok[ve * ECAP + sidx] : 0;
  const int tn = tid & 31, tt = tid >> 5;
  const int n4 = tn * 4, t4 = tt * 4;

  float acc[4][4] = {};
  for (int k0 = 0; k0 < 1024; k0 += 32) {
    const float4 xv = *(const float4*)(xsrc + (size_t)tok * 1024 + k0 + kq * 4);
    float4 wv[4];
#pragma unroll
    for (int i = 0; i < 4; ++i) {
      const int idx = tid + i * 256;
      const int kk = idx >> 5, nq = idx & 31;
      wv[i] = *(const float4*)(w1 + (size_t)(k0 + kk) * 512 + n0 + nq * 4);
    }
    __syncthreads();
    xs[kq * 4 + 0][tokr] = xv.x; xs[kq * 4 + 1][tokr] = xv.y;
    xs[kq * 4 + 2][tokr] = xv.z; xs[kq * 4 + 3][tokr] = xv.w;
#pragma unroll
    for (int i = 0; i < 4; ++i) {
      const int idx = tid + i * 256;
      const int kk = idx >> 5, nq = idx & 31;
      *(float4*)&ws[kk][nq * 4] = wv[i];
    }
    __syncthreads();
#pragma unroll
    for (int k = 0; k < 32; ++k) {
      const float4 xr = *(const float4*)&xs[k][t4];
      const float4 wr = *(const float4*)&ws[k][n4];
      const float xa[4] = {xr.x, xr.y, xr.z, xr.w};
      const float wa[4] = {wr.x, wr.y, wr.z, wr.w};
#pragma unroll
      for (int ti = 0; ti < 4; ++ti)
#pragma unroll
        for (int ni = 0; ni < 4; ++ni)
          acc[ti][ni] = fmaf(xa[ti], wa[ni], acc[ti][ni]);
    }
  }
#pragma unroll
  for (int ti = 0; ti < 4; ++ti) {
    float* hp = hbuf + ((size_t)ve * ECAP + tbase + t4 + ti) * 512 + n0 + n4;
#pragma unroll
    for (int ni = 0; ni < 4; ++ni)
      hp[ni] = fmaxf(acc[ti][ni] + B1[e * 512 + n0 + n4 + ni], 0.f);
  }
}

// ------- MoE FFN part 2: y = h @ W2 + b2 -------
__global__ __launch_bounds__(256) void moe_ffn2(const float* __restrict__ hbuf,
                                                const int* __restrict__ cnt,
                                                const float* __restrict__ W2,
                                                const float* __restrict__ B2,
                                                float* __restrict__ ybuf) {
  const int ve = blockIdx.x >> 6;
  const int rem = blockIdx.x & 63;
  const int tchunk = rem >> 3;
  const int nchunk = rem & 7;
  const int tbase = tchunk * 32;
  const int scnt = cnt[ve];
  if (tbase >= scnt) return;
  const int n0 = nchunk * 128;
  const int e = ve & 7;
  const float* __restrict__ w2 = W2 + (size_t)e * 512 * 1024;

  __shared__ float hs[32][36];
  __shared__ float ws[32][128];

  const int tid = threadIdx.x;
  const int tokr = tid >> 3, kq = tid & 7;
  const int tn = tid & 31, tt = tid >> 5;
  const int n4 = tn * 4, t4 = tt * 4;

  float acc[4][4] = {};
  for (int k0 = 0; k0 < 512; k0 += 32) {
    const float4 hv = *(const float4*)(hbuf + ((size_t)ve * ECAP + tbase + tokr) * 512 + k0 + kq * 4);
    float4 wv[4];
#pragma unroll
    for (int i = 0; i < 4; ++i) {
      const int idx = tid + i * 256;
      const int kk = idx >> 5, nq = idx & 31;
      wv[i] = *(const float4*)(w2 + (size_t)(k0 + kk) * 1024 + n0 + nq * 4);
    }
    __syncthreads();
    hs[kq * 4 + 0][tokr] = hv.x; hs[kq * 4 + 1][tokr] = hv.y;
    hs[kq * 4 + 2][tokr] = hv.z; hs[kq * 4 + 3][tokr] = hv.w;
#pragma unroll
    for (int i = 0; i < 4; ++i) {
      const int idx = tid + i * 256;
      const int kk = idx >> 5, nq = idx & 31;
      *(float4*)&ws[kk][nq * 4] = wv[i];
    }
    __syncthreads();
#pragma unroll
    for (int k = 0; k < 32; ++k) {
      const float4 xr = *(const float4*)&hs[k][t4];
      const float4 wr = *(const float4*)&ws[k][n4];
      const float xa[4] = {xr.x, xr.y, xr.z, xr.w};
      const float wa[4] = {wr.x, wr.y, wr.z, wr.w};
#pragma unroll
      for (int ti = 0; ti < 4; ++ti)
#pragma unroll
        for (int ni = 0; ni < 4; ++ni)
          acc[ti][ni] = fmaf(xa[ti], wa[ni], acc[ti][ni]);
    }
  }
#pragma unroll
  for (int ti = 0; ti < 4; ++ti) {
    float* yp = ybuf + ((size_t)ve * ECAP + tbase + t4 + ti) * 1024 + n0 + n4;
#pragma unroll
    for (int ni = 0; ni < 4; ++ni)
      yp[ni] = acc[ti][ni] + B2[e * 1024 + n0 + n4 + ni];
  }
}

// ------- combine: z[b] = w0*y[slot0] + w1*y[slot1] -------
__global__ __launch_bounds__(256) void moe_combine(const float* __restrict__ ybuf,
                                                   const int* __restrict__ slot_of,
                                                   const float* __restrict__ sel_w,
                                                   float* __restrict__ z_img,
                                                   float* __restrict__ z_txt) {
  const int bb = blockIdx.x;
  const int mod = bb >> 8;
  const int b = bb & 255;
  const int s0 = slot_of[bb * 2], s1 = slot_of[bb * 2 + 1];
  const float w0 = sel_w[bb * 2], w1 = sel_w[bb * 2 + 1];
  float* __restrict__ zp = (mod ? z_txt : z_img) + (size_t)b * 1024;
  const float* __restrict__ y0 = ybuf + (size_t)s0 * 1024;
  const float* __restrict__ y1 = ybuf + (size_t)s1 * 1024;
  const int t = threadIdx.x;
#pragma unroll
  for (int dd = 0; dd < 4; ++dd) {
    const int d = t + dd * 256;
    zp[d] = w0 * y0[d] + w1 * y1[d];
  }
}

// ------- projection GEMM: [512 tokens x 1024] @ W[1024x1024] (no bias) -------
__global__ __launch_bounds__(256) void proj_gemm(const float* __restrict__ z_img,
                                                 const float* __restrict__ z_txt,
                                                 const float* __restrict__ Wimg,
                                                 const float* __restrict__ Wtxt,
                                                 float* __restrict__ e_img,
                                                 float* __restrict__ e_txt) {
  const int bid = blockIdx.x;
  const int mod = bid >> 6;
  const int tchunk = (bid >> 3) & 7;
  const int nchunk = bid & 7;
  const int tbase = tchunk * 32;
  const int n0 = nchunk * 128;
  const float* __restrict__ x = mod ? z_txt : z_img;
  const float* __restrict__ W = mod ? Wtxt : Wimg;
  float* __restrict__ P = mod ? e_txt : e_img;

  __shared__ float xs[32][36];
  __shared__ float ws[32][128];

  const int tid = threadIdx.x;
  const int tokr = tid >> 3, kq = tid & 7;
  const int tn = tid & 31, tt = tid >> 5;
  const int n4 = tn * 4, t4 = tt * 4;

  float acc[4][4] = {};
  for (int k0 = 0; k0 < 1024; k0 += 32) {
    const float4 xv = *(const float4*)(x + (size_t)(tbase + tokr) * 1024 + k0 + kq * 4);
    float4 wv[4];
#pragma unroll
    for (int i = 0; i < 4; ++i) {
      const int idx = tid + i * 256;
      const int kk = idx >> 5, nq = idx & 31;
      wv[i] = *(const float4*)(W + (size_t)(k0 + kk) * 1024 + n0 + nq * 4);
    }
    __syncthreads();
    xs[kq * 4 + 0][tokr] = xv.x; xs[kq * 4 + 1][tokr] = xv.y;
    xs[kq * 4 + 2][tokr] = xv.z; xs[kq * 4 + 3][tokr] = xv.w;
#pragma unroll
    for (int i = 0; i < 4; ++i) {
      const int idx = tid + i * 256;
      const int kk = idx >> 5, nq = idx & 31;
      *(float4*)&ws[kk][nq * 4] = wv[i];
    }
    __syncthreads();
#pragma unroll
    for (int k = 0; k < 32; ++k) {
      const float4 xr = *(const float4*)&xs[k][t4];
      const float4 wr = *(const float4*)&ws[k][n4];
      const float xa[4] = {xr.x, xr.y, xr.z, xr.w};
      const float wa[4] = {wr.x, wr.y, wr.z, wr.w};
#pragma unroll
      for (int ti = 0; ti < 4; ++ti)
#pragma unroll
        for (int ni = 0; ni < 4; ++ni)
          acc[ti][ni] = fmaf(xa[ti], wa[ni], acc[ti][ni]);
    }
  }
#pragma unroll
  for (int ti = 0; ti < 4; ++ti) {
    float* pp = P + (size_t)(tbase + t4 + ti) * 1024 + n0 + n4;
#pragma unroll
    for (int ni = 0; ni < 4; ++ni) pp[ni] = acc[ti][ni];
  }
}

// ------- row L2-normalize in place (512 rows of 1024) -------
__global__ __launch_bounds__(256) void norm_rows(float* __restrict__ p) {
  const int b = blockIdx.x;
  const int t = threadIdx.x;
  __shared__ float red[256];
  float* __restrict__ row = p + (size_t)b * 1024;
  float4 v = *(const float4*)(row + t * 4);
  float ss = v.x * v.x + v.y * v.y + v.z * v.z + v.w * v.w;
  red[t] = ss;
  __syncthreads();
  for (int off = 128; off; off >>= 1) {
    if (t < off) red[t] += red[t + off];
    __syncthreads();
  }
  const float inv = 1.f / fmaxf(sqrtf(red[0]), 1e-12f);
  v.x *= inv; v.y *= inv; v.z *= inv; v.w *= inv;
  *(float4*)(row + t * 4) = v;
}

// ---------------- logits: scale * e_img @ e_txt^T (+ transpose) ----------------
__global__ __launch_bounds__(256) void clip_logits(const float* __restrict__ ei,
                                                   const float* __restrict__ et,
                                                   const float* __restrict__ logit_scale,
                                                   float* __restrict__ out_pi,
                                                   float* __restrict__ out_pt) {
  const int i = blockIdx.x;
  const int j = threadIdx.x;
  __shared__ float row[1024];
#pragma unroll
  for (int c = 0; c < 4; ++c) row[j + c * 256] = ei[i * 1024 + j + c * 256];
  __syncthreads();
  float acc = 0.f;
  const float4* __restrict__ tp = (const float4*)(et + (size_t)j * 1024);
  for (int d = 0; d < 256; ++d) {
    const float4 tv = tp[d];
    const float4 rv = *(const float4*)&row[d * 4];
    acc = fmaf(rv.x, tv.x, acc);
    acc = fmaf(rv.y, tv.y, acc);
    acc = fmaf(rv.z, tv.z, acc);
    acc = fmaf(rv.w, tv.w, acc);
  }
  const float s = fminf(expf(logit_scale[0]), 100.f);
  const float v = s * acc;
  out_pi[i * 256 + j] = v;
  out_pt[j * 256 + i] = v;
}

// ---------------- aux loss (deterministic fixed-order reduce) ----------------
__global__ __launch_bounds__(256) void aux_kernel(const float* __restrict__ probs_i,
                                                  const float* __restrict__ probs_t,
                                                  float* __restrict__ out_aux) {
  __shared__ float red[256];
  const int t = threadIdx.x;
  float aux[2];
  for (int m = 0; m < 2; ++m) {
    const float* __restrict__ p = m ? probs_t : probs_i;
    float a = 0.f;
    for (int e = 0; e < 8; ++e) {
      red[t] = p[t * 8 + e];
      __syncthreads();
      for (int off = 128; off; off >>= 1) {
        if (t < off) red[t] += red[t + off];
        __syncthreads();
      }
      const float mp = red[0] * (1.f / 256.f);
      a += 0.125f * (logf(0.125f) - logf(mp));
      __syncthreads();
    }
    aux[m] = a * 0.125f;
  }
  if (t == 0) out_aux[0] = 0.5f * (aux[0] + aux[1]);
}

extern "C" void kernel_launch(void* const* d_in, const int* in_sizes, int n_in,
                              void* d_out, int out_size, void* d_ws, size_t ws_size,
                              hipStream_t stream) {
  const float* img        = (const float*)d_in[0];
  const int*   tokens     = (const int*)d_in[1];
  const int*   mask       = (const int*)d_in[2];
  const float* cw1        = (const float*)d_in[3];
  const float* cb1        = (const float*)d_in[4];
  const float* cw2        = (const float*)d_in[5];
  const float* cb2        = (const float*)d_in[6];
  const float* cw3        = (const float*)d_in[7];
  const float* cb3        = (const float*)d_in[8];
  const float* cw4        = (const float*)d_in[9];
  const float* cb4        = (const float*)d_in[10];
  const float* enc_proj_w = (const float*)d_in[11];
  const float* enc_proj_b = (const float*)d_in[12];
  const float* embed      = (const float*)d_in[13];
  const float* gate_w     = (const float*)d_in[14];
  const float* gate_b     = (const float*)d_in[15];
  const float* exp_w1     = (const float*)d_in[16];
  const float* exp_b1     = (const float*)d_in[17];
  const float* exp_w2     = (const float*)d_in[18];
  const float* exp_b2     = (const float*)d_in[19];
  const float* img_proj_w = (const float*)d_in[20];
  const float* txt_proj_w = (const float*)d_in[21];
  const float* logit_sc   = (const float*)d_in[22];
  float* out = (float*)d_out;

  // ---- dynamic chunk: largest that fits ws. Tail = exact requirement
  // (1,648,656 floats) so the chunk=32 fallback needs exactly the
  // 107,257,920-byte footprint verified by the round-2 passing run.
  const size_t tail_floats = 1648656;
  int chunk = 32;
  for (int c = 256; c >= 32; c >>= 1) {
    const size_t need = ((size_t)c * 786432 + tail_floats) * 4;
    if (need <= ws_size) { chunk = c; break; }
  }
  const int nchunk = BATCH / chunk;

  // workspace layout (floats)
  float* bufA   = (float*)d_ws;                      // chunk * 524288
  float* bufB   = bufA + (size_t)chunk * 524288;     // chunk * 262144
  float* pooled = bufB + (size_t)chunk * 262144;     // 65,536
  float* h_img  = pooled + 65536;                    // 262,144 each
  float* h_txt  = h_img + 262144;
  float* z_img  = h_txt + 262144;
  float* z_txt  = z_img + 262144;
  float* e_img  = z_txt + 262144;                    // e_img/e_txt contiguous
  float* e_txt  = e_img + 262144;
  float* probs_img = e_txt + 262144;                 // 2048
  float* probs_txt = probs_img + 2048;               // 2048
  float* sel_w  = probs_txt + 2048;                  // 1024
  int* slot_of  = (int*)(sel_w + 1024);              // 1024
  int* slot_tok = slot_of + 1024;                    // 4096
  int* cnt      = slot_tok + 4096;                   // 16
  // MoE intermediates overlay bufA (convs done before MoE)
  float* hbuf = bufA;                                // 4096 x 512
  float* ybuf = bufA + (size_t)NEXP * ECAP * 512;    // 4096 x 1024

  zero_cnt<<<1, 64, 0, stream>>>(cnt);

  // ---- image encoder ----
  for (int c = 0; c < nchunk; ++c) {
    const float* imgc = img + (size_t)c * chunk * 3 * 128 * 128;
    conv1_tiled<<<chunk * 32 * 4, 256, 0, stream>>>(imgc, cw1, cb1, bufA);
    conv_s2_r4<32, 128, 128, 64, 64, 64, 2, 8, 4>
        <<<chunk * 16, 256, 0, stream>>>(bufA, cw2, cb2, bufB);
    conv_s2_r4<64, 64, 64, 32, 32, 128, 2, 8, 1>
        <<<chunk * 8, 256, 0, stream>>>(bufB, cw3, cb3, bufA);
    conv4_pool<<<chunk * 16, 256, 0, stream>>>(bufA, cw4, cb4,
                                               pooled + (size_t)c * chunk * 256);
  }
  enc_proj<<<BATCH, 256, 0, stream>>>(pooled, enc_proj_w, enc_proj_b, h_img);

  // ---- text encoder ----
  txt_encode<<<BATCH, 256, 0, stream>>>(tokens, mask, embed, h_txt);

  // ---- MoE ----
  gate_topk<<<BATCH, 256, 0, stream>>>(h_img, gate_w, gate_b, probs_img,
                                       sel_w, slot_of, cnt, slot_tok, 0);
  gate_topk<<<BATCH, 256, 0, stream>>>(h_txt, gate_w, gate_b, probs_txt,
                                       sel_w + 512, slot_of + 512, cnt, slot_tok, 8);
  moe_ffn1<<<NEXP * 32, 256, 0, stream>>>(h_img, h_txt, cnt, slot_tok,
                                          exp_w1, exp_b1, hbuf);
  moe_ffn2<<<NEXP * 64, 256, 0, stream>>>(hbuf, cnt, exp_w2, exp_b2, ybuf);
  moe_combine<<<512, 256, 0, stream>>>(ybuf, slot_of, sel_w, z_img, z_txt);

  // ---- contrastive head ----
  proj_gemm<<<128, 256, 0, stream>>>(z_img, z_txt, img_proj_w, txt_proj_w, e_img, e_txt);
  norm_rows<<<512, 256, 0, stream>>>(e_img);  // e_img/e_txt contiguous: 512 rows
  clip_logits<<<BATCH, 256, 0, stream>>>(e_img, e_txt, logit_sc, out, out + 65536);
  aux_kernel<<<1, 256, 0, stream>>>(probs_img, probs_txt, out + 131072);
}